// Round 4
// baseline (618.570 us; speedup 1.0000x reference)
//
#include <hip/hip_runtime.h>
#include <hip/hip_fp16.h>
#include <hip/hip_cooperative_groups.h>

namespace cg = cooperative_groups;

constexpr int BLK = 256;

static inline int cdiv(long long a, int b) { return (int)((a + b - 1) / b); }

using v8h = __attribute__((ext_vector_type(8))) _Float16;
using v4f = __attribute__((ext_vector_type(4))) float;

// ---------------- CSR build: one cooperative kernel, 6 phases ----------------
// Replaces zero_int/count_dst_off/scan1_dis/scan2z/scan3/csr_fill (6 dispatches
// -> 1). ~10us/dispatch launch overhead made the split version dominate.
// Phases separated by grid.sync(); logic identical to the split kernels.

__global__ __launch_bounds__(256) void csr_build(const int* __restrict__ src,
                                                 const int* __restrict__ dst,
                                                 int* __restrict__ cnt,
                                                 int* __restrict__ rowptr,
                                                 int* __restrict__ bsum,
                                                 int* __restrict__ boff,
                                                 float* __restrict__ dis,
                                                 unsigned short* __restrict__ eoff,
                                                 unsigned short* __restrict__ csrc,
                                                 float* __restrict__ sums,
                                                 int N, int E) {
    cg::grid_group grid = cg::this_grid();
    const int tid = threadIdx.x;
    const int gid = blockIdx.x * blockDim.x + tid;
    const int gsz = gridDim.x * blockDim.x;
    const int nb = (N + 1023) >> 10;
    __shared__ int ts[256];

    // phase A: zero cnt + BN sums buffer
    for (int i = gid; i < N; i += gsz) cnt[i] = 0;
    if (gid < 576) sums[gid] = 0.0f;
    grid.sync();

    // phase B: in-degree count; per-edge within-node offset (deg < 64K)
    for (int i = gid; i < E; i += gsz)
        eoff[i] = (unsigned short)atomicAdd(&cnt[dst[i]], 1);
    grid.sync();

    // phase C: per-chunk scan (1024 elems/chunk) + dis = rsqrt(cnt+1)
    for (int b = blockIdx.x; b < nb; b += gridDim.x) {
        int base = b * 1024 + tid * 4;
        int v[4], s = 0;
#pragma unroll
        for (int i = 0; i < 4; ++i) {
            v[i] = (base + i < N) ? cnt[base + i] : 0;
            s += v[i];
            if (base + i < N) dis[base + i] = rsqrtf((float)v[i] + 1.0f);
        }
        ts[tid] = s;
        __syncthreads();
        for (int off = 1; off < 256; off <<= 1) {
            int t = 0;
            if (tid >= off) t = ts[tid - off];
            __syncthreads();
            if (tid >= off) ts[tid] += t;
            __syncthreads();
        }
        int run = ts[tid] - s;
#pragma unroll
        for (int i = 0; i < 4; ++i) {
            if (base + i < N) rowptr[base + i] = run;
            run += v[i];
        }
        if (tid == 255) bsum[b] = ts[255];
        __syncthreads();
    }
    grid.sync();

    // phase D: block 0, wave 0 scans the <=64 chunk sums
    if (blockIdx.x == 0 && tid < 64) {
        int orig = (tid < nb) ? bsum[tid] : 0;
        int v = orig;
#pragma unroll
        for (int off = 1; off < 64; off <<= 1) {
            int t = __shfl_up(v, off, 64);
            if (tid >= off) v += t;
        }
        if (tid < nb) boff[tid] = v - orig;  // exclusive
    }
    grid.sync();

    // phase E: add chunk offsets; terminate rowptr
    for (int i = gid; i < N; i += gsz) rowptr[i] += boff[i >> 10];
    if (gid == 0) rowptr[N] = E;
    grid.sync();

    // phase F: atomic-free scatter of 2-B src index (slot bijection)
    for (int i = gid; i < E; i += gsz)
        csrc[rowptr[dst[i]] + (int)eoff[i]] = (unsigned short)src[i];
}

// ---------------- MFMA GEMM: act(in)[N,K] @ W[K,96] (+bias) -----------------
// A: fp32 -> BN+ReLU -> fp16 frags in regs. B: W^T fp16 in LDS (one barrier).
// ACT: BN scale/shift computed in-block from (bnsums, gamma, beta).
// STATS: epilogue accumulates column sum/sumsq into osums.
// HOUT: fp16 shadow output is PRE-SCALED by dsc[row] (= dis[row]) so the
// aggregation kernel needs no per-edge dis gather:
//   out[n] = b + dn^2 h[n] + dn * sum dis[s] h[s] = b + dn*(hs[n] + sum hs[s])

template <int K, bool ACT, bool BIAS, bool HOUT, bool WOUT, bool STATS>
__global__ __launch_bounds__(256) void gemm96m(const float* __restrict__ in,
                                               const float* __restrict__ W,
                                               const float* __restrict__ bias,
                                               const float* __restrict__ bnsums,
                                               const float* __restrict__ gamma,
                                               const float* __restrict__ beta,
                                               const float* __restrict__ dsc,
                                               float* __restrict__ out,
                                               _Float16* __restrict__ hout,
                                               float* __restrict__ osums, int N) {
    constexpr int NK = K / 32;
    constexpr int LDK = K + 8;
    __shared__ __align__(16) _Float16 Wt[96 * LDK];
    __shared__ __align__(16) float ssl[ACT ? 192 : 1];
    __shared__ float sb[STATS ? 192 : 1];
    const int tid = threadIdx.x;
    for (int idx = tid; idx < K * 96; idx += 256) {
        int k = idx / 96, n = idx - k * 96;
        Wt[n * LDK + k] = (_Float16)W[idx];
    }
    if (ACT && tid < 96) {
        float inv_n = 1.0f / (float)N;
        float mean = bnsums[tid] * inv_n;
        float var = bnsums[96 + tid] * inv_n - mean * mean;
        float sc = gamma[tid] * rsqrtf(var + 1e-5f);
        ssl[tid] = sc;
        ssl[96 + tid] = beta[tid] - mean * sc;
    }
    if (STATS && tid < 192) sb[tid] = 0.0f;
    __syncthreads();

    const int wave = tid >> 6, lane = tid & 63;
    const int quad = lane >> 4, lm = lane & 15;
    const int rbase = blockIdx.x * 64 + wave * 16;
    int arow = rbase + lm;
    arow = arow < N ? arow : N - 1;

    v8h afr[NK];
#pragma unroll
    for (int kc = 0; kc < NK; ++kc) {
        const float* p = &in[(long long)arow * K + kc * 32 + quad * 8];
        float4 p0 = *(const float4*)p;
        float4 p1 = *(const float4*)(p + 4);
        if (ACT) {
            int kk = kc * 32 + quad * 8;
            float4 sc0 = *(const float4*)&ssl[kk];
            float4 sc1 = *(const float4*)&ssl[kk + 4];
            float4 sh0 = *(const float4*)&ssl[96 + kk];
            float4 sh1 = *(const float4*)&ssl[96 + kk + 4];
            p0.x = fmaxf(fmaf(p0.x, sc0.x, sh0.x), 0.0f);
            p0.y = fmaxf(fmaf(p0.y, sc0.y, sh0.y), 0.0f);
            p0.z = fmaxf(fmaf(p0.z, sc0.z, sh0.z), 0.0f);
            p0.w = fmaxf(fmaf(p0.w, sc0.w, sh0.w), 0.0f);
            p1.x = fmaxf(fmaf(p1.x, sc1.x, sh1.x), 0.0f);
            p1.y = fmaxf(fmaf(p1.y, sc1.y, sh1.y), 0.0f);
            p1.z = fmaxf(fmaf(p1.z, sc1.z, sh1.z), 0.0f);
            p1.w = fmaxf(fmaf(p1.w, sc1.w, sh1.w), 0.0f);
        }
        v8h a;
        a[0] = (_Float16)p0.x; a[1] = (_Float16)p0.y;
        a[2] = (_Float16)p0.z; a[3] = (_Float16)p0.w;
        a[4] = (_Float16)p1.x; a[5] = (_Float16)p1.y;
        a[6] = (_Float16)p1.z; a[7] = (_Float16)p1.w;
        afr[kc] = a;
    }

    v4f acc[6];
#pragma unroll
    for (int t = 0; t < 6; ++t) {
        v4f c = {0.0f, 0.0f, 0.0f, 0.0f};
#pragma unroll
        for (int kc = 0; kc < NK; ++kc) {
            v8h b = *(const v8h*)&Wt[(t * 16 + lm) * LDK + kc * 32 + quad * 8];
            c = __builtin_amdgcn_mfma_f32_16x16x32_f16(afr[kc], b, c, 0, 0, 0);
        }
        acc[t] = c;
    }

    float dr[4];
    if (HOUT) {
#pragma unroll
        for (int r = 0; r < 4; ++r) {
            int gr = rbase + quad * 4 + r;
            dr[r] = dsc[gr < N ? gr : N - 1];
        }
    }

    float ls[6], lq[6];
#pragma unroll
    for (int t = 0; t < 6; ++t) { ls[t] = 0.0f; lq[t] = 0.0f; }
#pragma unroll
    for (int t = 0; t < 6; ++t) {
        float bv = BIAS ? bias[t * 16 + lm] : 0.0f;
#pragma unroll
        for (int r = 0; r < 4; ++r) {
            int gr = rbase + quad * 4 + r;
            if (gr < N) {
                float o = acc[t][r] + bv;
                if (WOUT) out[(long long)gr * 96 + t * 16 + lm] = o;
                if (HOUT) hout[(long long)gr * 96 + t * 16 + lm] = (_Float16)(o * dr[r]);
                if (STATS) { ls[t] += o; lq[t] += o * o; }
            }
        }
    }
    if (STATS) {
#pragma unroll
        for (int t = 0; t < 6; ++t) {
            ls[t] += __shfl_xor(ls[t], 16);
            ls[t] += __shfl_xor(ls[t], 32);
            lq[t] += __shfl_xor(lq[t], 16);
            lq[t] += __shfl_xor(lq[t], 32);
        }
        if (quad == 0) {
#pragma unroll
            for (int t = 0; t < 6; ++t) {
                atomicAdd(&sb[t * 16 + lm], ls[t]);
                atomicAdd(&sb[96 + t * 16 + lm], lq[t]);
            }
        }
        __syncthreads();
        if (tid < 192) atomicAdd(&osums[tid], sb[tid]);
    }
}

// ---------------- MFMA final GEMM: l2norm(act(in) @ Wp2[96,64] + bp2) -------

__global__ __launch_bounds__(256) void gemm_finalm(const float* __restrict__ in,
                                                   const float* __restrict__ W,
                                                   const float* __restrict__ bias,
                                                   const float* __restrict__ bnsums,
                                                   const float* __restrict__ gamma,
                                                   const float* __restrict__ beta,
                                                   float* __restrict__ out, int N) {
    constexpr int K = 96, NK = 3, LDK = K + 8;
    __shared__ __align__(16) _Float16 Wt[64 * LDK];
    __shared__ __align__(16) float ssl[192];
    const int tid = threadIdx.x;
    for (int idx = tid; idx < K * 64; idx += 256) {
        int k = idx / 64, n = idx - k * 64;
        Wt[n * LDK + k] = (_Float16)W[idx];
    }
    if (tid < 96) {
        float inv_n = 1.0f / (float)N;
        float mean = bnsums[tid] * inv_n;
        float var = bnsums[96 + tid] * inv_n - mean * mean;
        float sc = gamma[tid] * rsqrtf(var + 1e-5f);
        ssl[tid] = sc;
        ssl[96 + tid] = beta[tid] - mean * sc;
    }
    __syncthreads();

    const int wave = tid >> 6, lane = tid & 63;
    const int quad = lane >> 4, lm = lane & 15;
    const int rbase = blockIdx.x * 64 + wave * 16;
    int arow = rbase + lm;
    arow = arow < N ? arow : N - 1;

    v8h afr[NK];
#pragma unroll
    for (int kc = 0; kc < NK; ++kc) {
        const float* p = &in[(long long)arow * K + kc * 32 + quad * 8];
        float4 p0 = *(const float4*)p;
        float4 p1 = *(const float4*)(p + 4);
        int kk = kc * 32 + quad * 8;
        float4 sc0 = *(const float4*)&ssl[kk];
        float4 sc1 = *(const float4*)&ssl[kk + 4];
        float4 sh0 = *(const float4*)&ssl[96 + kk];
        float4 sh1 = *(const float4*)&ssl[96 + kk + 4];
        p0.x = fmaxf(fmaf(p0.x, sc0.x, sh0.x), 0.0f);
        p0.y = fmaxf(fmaf(p0.y, sc0.y, sh0.y), 0.0f);
        p0.z = fmaxf(fmaf(p0.z, sc0.z, sh0.z), 0.0f);
        p0.w = fmaxf(fmaf(p0.w, sc0.w, sh0.w), 0.0f);
        p1.x = fmaxf(fmaf(p1.x, sc1.x, sh1.x), 0.0f);
        p1.y = fmaxf(fmaf(p1.y, sc1.y, sh1.y), 0.0f);
        p1.z = fmaxf(fmaf(p1.z, sc1.z, sh1.z), 0.0f);
        p1.w = fmaxf(fmaf(p1.w, sc1.w, sh1.w), 0.0f);
        v8h a;
        a[0] = (_Float16)p0.x; a[1] = (_Float16)p0.y;
        a[2] = (_Float16)p0.z; a[3] = (_Float16)p0.w;
        a[4] = (_Float16)p1.x; a[5] = (_Float16)p1.y;
        a[6] = (_Float16)p1.z; a[7] = (_Float16)p1.w;
        afr[kc] = a;
    }

    v4f acc[4];
#pragma unroll
    for (int t = 0; t < 4; ++t) {
        v4f c = {0.0f, 0.0f, 0.0f, 0.0f};
#pragma unroll
        for (int kc = 0; kc < NK; ++kc) {
            v8h b = *(const v8h*)&Wt[(t * 16 + lm) * LDK + kc * 32 + quad * 8];
            c = __builtin_amdgcn_mfma_f32_16x16x32_f16(afr[kc], b, c, 0, 0, 0);
        }
        float bv = bias[t * 16 + lm];
        c[0] += bv; c[1] += bv; c[2] += bv; c[3] += bv;
        acc[t] = c;
    }

    float sq[4];
#pragma unroll
    for (int r = 0; r < 4; ++r) {
        float s = acc[0][r] * acc[0][r] + acc[1][r] * acc[1][r] +
                  acc[2][r] * acc[2][r] + acc[3][r] * acc[3][r];
#pragma unroll
        for (int m = 1; m < 16; m <<= 1) s += __shfl_xor(s, m, 64);
        sq[r] = 1.0f / fmaxf(sqrtf(s), 1e-12f);
    }
#pragma unroll
    for (int r = 0; r < 4; ++r) {
        int gr = rbase + quad * 4 + r;
        if (gr < N) {
#pragma unroll
            for (int t = 0; t < 4; ++t)
                out[(long long)gr * 64 + t * 16 + lm] = acc[t][r] * sq[r];
        }
    }
}

// ---------------- CSR pull aggregation (fp16 gather, 2-B edge index) ---------
// Rows in hxw are pre-scaled by dis[src] at GEMM-epilogue time, so:
//   out[n] = bias + dis[n] * (hxw[n] + sum_e hxw[src_e])
// 12 threads/node, 8 cols each, edge loop unrolled x8/x4 (R9-proven batching).

__device__ __forceinline__ void acc_row(float* acc, const __half2* h) {
#pragma unroll
    for (int k = 0; k < 4; ++k) {
        float2 f = __half22float2(h[k]);
        acc[2 * k + 0] += f.x;
        acc[2 * k + 1] += f.y;
    }
}

__global__ __launch_bounds__(256) void agg96h(const __half* __restrict__ hxw,
                                              const int* __restrict__ rowptr,
                                              const unsigned short* __restrict__ csrc,
                                              const float* __restrict__ dis,
                                              const float* __restrict__ bias,
                                              float* __restrict__ out, int N) {
    int idx = blockIdx.x * 256 + threadIdx.x;
    if (idx >= N * 12) return;
    int n = idx / 12, c8 = idx % 12;
    int ch = c8 * 8;
    float acc[8];
    {
        float4 g = *(const float4*)&hxw[(long long)n * 96 + ch];
        const __half2* hs = (const __half2*)&g;
#pragma unroll
        for (int k = 0; k < 4; ++k) {
            float2 f = __half22float2(hs[k]);
            acc[2 * k + 0] = f.x;
            acc[2 * k + 1] = f.y;
        }
    }
    int e = rowptr[n], e1 = rowptr[n + 1];
    for (; e + 7 < e1; e += 8) {
        int s[8];
        float4 g[8];
#pragma unroll
        for (int j = 0; j < 8; ++j) s[j] = csrc[e + j];
#pragma unroll
        for (int j = 0; j < 8; ++j)
            g[j] = *(const float4*)&hxw[(long long)s[j] * 96 + ch];
#pragma unroll
        for (int j = 0; j < 8; ++j) acc_row(acc, (const __half2*)&g[j]);
    }
    for (; e + 3 < e1; e += 4) {
        int s[4];
        float4 g[4];
#pragma unroll
        for (int j = 0; j < 4; ++j) s[j] = csrc[e + j];
#pragma unroll
        for (int j = 0; j < 4; ++j)
            g[j] = *(const float4*)&hxw[(long long)s[j] * 96 + ch];
#pragma unroll
        for (int j = 0; j < 4; ++j) acc_row(acc, (const __half2*)&g[j]);
    }
    for (; e < e1; ++e) {
        int s0 = csrc[e];
        float4 g0 = *(const float4*)&hxw[(long long)s0 * 96 + ch];
        acc_row(acc, (const __half2*)&g0);
    }
    float dn = dis[n];
    float4 o0, o1;
    o0.x = fmaf(acc[0], dn, bias[ch + 0]);
    o0.y = fmaf(acc[1], dn, bias[ch + 1]);
    o0.z = fmaf(acc[2], dn, bias[ch + 2]);
    o0.w = fmaf(acc[3], dn, bias[ch + 3]);
    o1.x = fmaf(acc[4], dn, bias[ch + 4]);
    o1.y = fmaf(acc[5], dn, bias[ch + 5]);
    o1.z = fmaf(acc[6], dn, bias[ch + 6]);
    o1.w = fmaf(acc[7], dn, bias[ch + 7]);
    *(float4*)&out[(long long)n * 96 + ch] = o0;
    *(float4*)&out[(long long)n * 96 + ch + 4] = o1;
}

// ---------------- BN stats (coalesced grid-stride, for agg outputs) ----------
// grid must be a multiple of 3 blocks so stride = grid*256 is a multiple of 24
// (fixed c4 = g%24 requires i%24 invariant across the stride loop).

__global__ __launch_bounds__(256) void bn_stats96(const float* __restrict__ h,
                                                  float* __restrict__ sums, int N) {
    __shared__ float sb[192];
    const int tid = threadIdx.x;
    if (tid < 192) sb[tid] = 0.0f;
    __syncthreads();
    int g = blockIdx.x * 256 + tid;
    int total = N * 24, stride = gridDim.x * 256;
    float4 s4 = {0, 0, 0, 0}, q4 = {0, 0, 0, 0};
    int c4 = g % 24;
    for (int i = g; i < total; i += stride) {
        int n = i / 24;
        float4 v = *(const float4*)&h[n * 96 + 4 * c4];
        s4.x += v.x; s4.y += v.y; s4.z += v.z; s4.w += v.w;
        q4.x += v.x * v.x; q4.y += v.y * v.y; q4.z += v.z * v.z; q4.w += v.w * v.w;
    }
    atomicAdd(&sb[4 * c4 + 0], s4.x);
    atomicAdd(&sb[4 * c4 + 1], s4.y);
    atomicAdd(&sb[4 * c4 + 2], s4.z);
    atomicAdd(&sb[4 * c4 + 3], s4.w);
    atomicAdd(&sb[96 + 4 * c4 + 0], q4.x);
    atomicAdd(&sb[96 + 4 * c4 + 1], q4.y);
    atomicAdd(&sb[96 + 4 * c4 + 2], q4.z);
    atomicAdd(&sb[96 + 4 * c4 + 3], q4.w);
    __syncthreads();
    if (tid < 192) atomicAdd(&sums[tid], sb[tid]);
}

// ---------------- launch ----------------

extern "C" void kernel_launch(void* const* d_in, const int* in_sizes, int n_in,
                              void* d_out, int out_size, void* d_ws, size_t ws_size,
                              hipStream_t stream) {
    const float* x   = (const float*)d_in[0];
    const int*   ei  = (const int*)d_in[1];
    const float* W1  = (const float*)d_in[2];
    const float* b1  = (const float*)d_in[3];
    const float* g1  = (const float*)d_in[4];
    const float* be1 = (const float*)d_in[5];
    const float* W2  = (const float*)d_in[6];
    const float* b2  = (const float*)d_in[7];
    const float* g2  = (const float*)d_in[8];
    const float* be2 = (const float*)d_in[9];
    const float* Wp1 = (const float*)d_in[10];
    const float* bp1 = (const float*)d_in[11];
    const float* gp  = (const float*)d_in[12];
    const float* bep = (const float*)d_in[13];
    const float* Wp2 = (const float*)d_in[14];
    const float* bp2 = (const float*)d_in[15];

    const int N = in_sizes[0] / 128;   // 50000 (< 2^16 -> uint16 indices ok)
    const int E = in_sizes[1] / 2;     // 800000
    const int* src = ei;
    const int* dst = ei + E;

    // workspace layout (~50 MB)
    char* w = (char*)d_ws;
    auto alloc = [&](size_t bytes) { char* p = w; w += (bytes + 15) & ~size_t(15); return p; };
    int*            cnt    = (int*)alloc((size_t)N * 4);
    int*            rowptr = (int*)alloc((size_t)(N + 1) * 4);
    int*            bsum   = (int*)alloc(64 * 4);
    int*            boff   = (int*)alloc(64 * 4);
    float*          dis    = (float*)alloc((size_t)N * 4);
    unsigned short* eoff   = (unsigned short*)alloc((size_t)E * 2);
    unsigned short* csrc   = (unsigned short*)alloc((size_t)E * 2);
    float*          buf1   = (float*)alloc((size_t)N * 96 * 4);
    float*          buf2   = (float*)alloc((size_t)N * 96 * 4);
    _Float16*       hbuf   = (_Float16*)alloc((size_t)N * 96 * 2);
    float*          sums   = (float*)alloc(576 * 4);
    float* sums1 = sums, *sums2 = sums + 192, *sums3 = sums + 384;

    float* out = (float*)d_out;

    const int gG  = cdiv(N, 64);                   // 782 gemm blocks
    const int gA  = cdiv((long long)N * 12, BLK);  // 2344 agg blocks

    // CSR build: one cooperative kernel (512 blocks co-resident; tiny VGPR/LDS)
    {
        int Nv = N, Ev = E;
        void* args[] = {(void*)&src, (void*)&dst, (void*)&cnt, (void*)&rowptr,
                        (void*)&bsum, (void*)&boff, (void*)&dis, (void*)&eoff,
                        (void*)&csrc, (void*)&sums, (void*)&Nv, (void*)&Ev};
        hipLaunchCooperativeKernel((const void*)csr_build, dim3(512), dim3(256),
                                   args, 0, stream);
    }

    // layer 1: MFMA GEMM -> dis-scaled fp16 shadow; agg (no per-edge weights)
    gemm96m<128, false, false, true, false, false><<<gG, 256, 0, stream>>>(
        x, W1, nullptr, nullptr, nullptr, nullptr, dis, nullptr, hbuf, nullptr, N);
    agg96h<<<gA, 256, 0, stream>>>((const __half*)hbuf, rowptr, csrc, dis, b1, buf2, N);
    bn_stats96<<<510, 256, 0, stream>>>(buf2, sums1, N);

    // layer 2: BN1 finalize fused in-block; dis-scaled fp16 shadow out
    gemm96m<96, true, false, true, false, false><<<gG, 256, 0, stream>>>(
        buf2, W2, nullptr, sums1, g1, be1, dis, nullptr, hbuf, nullptr, N);
    agg96h<<<gA, 256, 0, stream>>>((const __half*)hbuf, rowptr, csrc, dis, b2, buf2, N);
    bn_stats96<<<510, 256, 0, stream>>>(buf2, sums2, N);

    // projector linear 1: BN2 finalize fused; fp32 out; BN3 stats fused
    gemm96m<96, true, true, false, true, true><<<gG, 256, 0, stream>>>(
        buf2, Wp1, bp1, sums2, g2, be2, nullptr, buf1, nullptr, sums3, N);

    // projector linear 2: BN3 finalize fused + bias + L2 normalize
    gemm_finalm<<<gG, 256, 0, stream>>>(buf1, Wp2, bp2, sums3, gp, bep, out, N);
}

// Round 6
// 333.703 us; speedup vs baseline: 1.8537x; 1.8537x over previous
//
#include <hip/hip_runtime.h>
#include <hip/hip_fp16.h>

constexpr int BLK = 256;

static inline int cdiv(long long a, int b) { return (int)((a + b - 1) / b); }

using v8h = __attribute__((ext_vector_type(8))) _Float16;
using v4f = __attribute__((ext_vector_type(4))) float;

// ---------------- degree / CSR build ----------------
// R4 lesson: cooperative grid.sync costs ~60us each on MI355X (8 XCDs) — never.
// R5 lesson: no cross-block spin-waits either (hang risk under replay).
// Dispatch reduction is done with safe merges only:
//   scan2z+scan3 -> scan23 (each apply-block redundantly wave-scans the 49
//                           chunk sums; no cross-block communication)
//   zero_int     -> merged into the layer-1 GEMM dispatch (independent work)

// count in-degree; record per-edge within-node offset as uint16 (deg < 64K)
__global__ void count_dst_off(const int* __restrict__ dst, int* __restrict__ cnt,
                              unsigned short* __restrict__ eoff, int E) {
    for (int i = blockIdx.x * blockDim.x + threadIdx.x; i < E; i += gridDim.x * blockDim.x)
        eoff[i] = (unsigned short)atomicAdd(&cnt[dst[i]], 1);
}

// block scans 1024 elements (256 threads x 4); also emits dis = rsqrt(cnt+1)
__global__ __launch_bounds__(256) void scan1_dis(const int* __restrict__ cnt,
                                                 int* __restrict__ rowptr,
                                                 int* __restrict__ bsum,
                                                 float* __restrict__ dis, int N) {
    __shared__ int ts[256];
    int tid = threadIdx.x;
    int base = blockIdx.x * 1024 + tid * 4;
    int v[4], s = 0;
#pragma unroll
    for (int i = 0; i < 4; ++i) {
        v[i] = (base + i < N) ? cnt[base + i] : 0;
        s += v[i];
        if (base + i < N) dis[base + i] = rsqrtf((float)v[i] + 1.0f);
    }
    ts[tid] = s;
    __syncthreads();
    for (int off = 1; off < 256; off <<= 1) {
        int t = 0;
        if (tid >= off) t = ts[tid - off];
        __syncthreads();
        if (tid >= off) ts[tid] += t;
        __syncthreads();
    }
    int run = ts[tid] - s;
#pragma unroll
    for (int i = 0; i < 4; ++i) {
        if (base + i < N) rowptr[base + i] = run;
        run += v[i];
    }
    if (tid == 255) bsum[blockIdx.x] = ts[255];
}

// merged scan2+scan3: every block wave-scans the <=64 chunk sums (L2-resident,
// redundant but free) and applies its chunk's exclusive offset to rowptr.
__global__ __launch_bounds__(256) void scan23(int* __restrict__ rowptr,
                                              const int* __restrict__ bsum,
                                              int nb, int N, int E) {
    __shared__ int sboff[64];
    const int tid = threadIdx.x;
    if (tid < 64) {
        int orig = (tid < nb) ? bsum[tid] : 0;
        int v = orig;
#pragma unroll
        for (int off = 1; off < 64; off <<= 1) {
            int t = __shfl_up(v, off, 64);
            if (tid >= off) v += t;
        }
        sboff[tid] = v - orig;  // exclusive prefix of chunk sums
    }
    __syncthreads();
    int i = blockIdx.x * 256 + tid;
    if (i < N) rowptr[i] += sboff[i >> 10];
    if (i == 0) rowptr[N] = E;
}

// atomic-free scatter of 2-B src index: slot = rowptr[dst] + eoff (bijection)
__global__ void csr_fill(const int* __restrict__ src, const int* __restrict__ dst,
                         const unsigned short* __restrict__ eoff,
                         const int* __restrict__ rowptr,
                         unsigned short* __restrict__ csrc, int E) {
    for (int i = blockIdx.x * blockDim.x + threadIdx.x; i < E; i += gridDim.x * blockDim.x) {
        csrc[rowptr[dst[i]] + (int)eoff[i]] = (unsigned short)src[i];
    }
}

// ---------------- MFMA GEMM body: act(in)[N,K] @ W[K,96] (+bias) ------------
// A: fp32 -> BN+ReLU -> fp16 frags in regs. B: W^T fp16 in LDS (one barrier).
// ACT: BN scale/shift computed in-block from (bnsums, gamma, beta).
// STATS: epilogue accumulates column sum/sumsq into osums.
// HOUT: fp16 shadow optionally PRE-SCALED by dsc[row] (dsc nullable at runtime).

template <int K, bool ACT, bool BIAS, bool HOUT, bool WOUT, bool STATS>
__device__ __forceinline__ void gemm96_body(int bid,
                                            const float* __restrict__ in,
                                            const float* __restrict__ W,
                                            const float* __restrict__ bias,
                                            const float* __restrict__ bnsums,
                                            const float* __restrict__ gamma,
                                            const float* __restrict__ beta,
                                            const float* __restrict__ dsc,
                                            float* __restrict__ out,
                                            _Float16* __restrict__ hout,
                                            float* __restrict__ osums, int N) {
    constexpr int NK = K / 32;
    constexpr int LDK = K + 8;
    __shared__ __align__(16) _Float16 Wt[96 * LDK];
    __shared__ __align__(16) float ssl[ACT ? 192 : 1];
    __shared__ float sb[STATS ? 192 : 1];
    const int tid = threadIdx.x;
    for (int idx = tid; idx < K * 96; idx += 256) {
        int k = idx / 96, n = idx - k * 96;
        Wt[n * LDK + k] = (_Float16)W[idx];
    }
    if (ACT && tid < 96) {
        float inv_n = 1.0f / (float)N;
        float mean = bnsums[tid] * inv_n;
        float var = bnsums[96 + tid] * inv_n - mean * mean;
        float sc = gamma[tid] * rsqrtf(var + 1e-5f);
        ssl[tid] = sc;
        ssl[96 + tid] = beta[tid] - mean * sc;
    }
    if (STATS && tid < 192) sb[tid] = 0.0f;
    __syncthreads();

    const int wave = tid >> 6, lane = tid & 63;
    const int quad = lane >> 4, lm = lane & 15;
    const int rbase = bid * 64 + wave * 16;
    int arow = rbase + lm;
    arow = arow < N ? arow : N - 1;

    v8h afr[NK];
#pragma unroll
    for (int kc = 0; kc < NK; ++kc) {
        const float* p = &in[(long long)arow * K + kc * 32 + quad * 8];
        float4 p0 = *(const float4*)p;
        float4 p1 = *(const float4*)(p + 4);
        if (ACT) {
            int kk = kc * 32 + quad * 8;
            float4 sc0 = *(const float4*)&ssl[kk];
            float4 sc1 = *(const float4*)&ssl[kk + 4];
            float4 sh0 = *(const float4*)&ssl[96 + kk];
            float4 sh1 = *(const float4*)&ssl[96 + kk + 4];
            p0.x = fmaxf(fmaf(p0.x, sc0.x, sh0.x), 0.0f);
            p0.y = fmaxf(fmaf(p0.y, sc0.y, sh0.y), 0.0f);
            p0.z = fmaxf(fmaf(p0.z, sc0.z, sh0.z), 0.0f);
            p0.w = fmaxf(fmaf(p0.w, sc0.w, sh0.w), 0.0f);
            p1.x = fmaxf(fmaf(p1.x, sc1.x, sh1.x), 0.0f);
            p1.y = fmaxf(fmaf(p1.y, sc1.y, sh1.y), 0.0f);
            p1.z = fmaxf(fmaf(p1.z, sc1.z, sh1.z), 0.0f);
            p1.w = fmaxf(fmaf(p1.w, sc1.w, sh1.w), 0.0f);
        }
        v8h a;
        a[0] = (_Float16)p0.x; a[1] = (_Float16)p0.y;
        a[2] = (_Float16)p0.z; a[3] = (_Float16)p0.w;
        a[4] = (_Float16)p1.x; a[5] = (_Float16)p1.y;
        a[6] = (_Float16)p1.z; a[7] = (_Float16)p1.w;
        afr[kc] = a;
    }

    v4f acc[6];
#pragma unroll
    for (int t = 0; t < 6; ++t) {
        v4f c = {0.0f, 0.0f, 0.0f, 0.0f};
#pragma unroll
        for (int kc = 0; kc < NK; ++kc) {
            v8h b = *(const v8h*)&Wt[(t * 16 + lm) * LDK + kc * 32 + quad * 8];
            c = __builtin_amdgcn_mfma_f32_16x16x32_f16(afr[kc], b, c, 0, 0, 0);
        }
        acc[t] = c;
    }

    float dr[4];
    if (HOUT) {
#pragma unroll
        for (int r = 0; r < 4; ++r) {
            int gr = rbase + quad * 4 + r;
            dr[r] = dsc ? dsc[gr < N ? gr : N - 1] : 1.0f;
        }
    }

    float ls[6], lq[6];
#pragma unroll
    for (int t = 0; t < 6; ++t) { ls[t] = 0.0f; lq[t] = 0.0f; }
#pragma unroll
    for (int t = 0; t < 6; ++t) {
        float bv = BIAS ? bias[t * 16 + lm] : 0.0f;
#pragma unroll
        for (int r = 0; r < 4; ++r) {
            int gr = rbase + quad * 4 + r;
            if (gr < N) {
                float o = acc[t][r] + bv;
                if (WOUT) out[(long long)gr * 96 + t * 16 + lm] = o;
                if (HOUT) hout[(long long)gr * 96 + t * 16 + lm] = (_Float16)(o * dr[r]);
                if (STATS) { ls[t] += o; lq[t] += o * o; }
            }
        }
    }
    if (STATS) {
#pragma unroll
        for (int t = 0; t < 6; ++t) {
            ls[t] += __shfl_xor(ls[t], 16);
            ls[t] += __shfl_xor(ls[t], 32);
            lq[t] += __shfl_xor(lq[t], 16);
            lq[t] += __shfl_xor(lq[t], 32);
        }
        if (quad == 0) {
#pragma unroll
            for (int t = 0; t < 6; ++t) {
                atomicAdd(&sb[t * 16 + lm], ls[t]);
                atomicAdd(&sb[96 + t * 16 + lm], lq[t]);
            }
        }
        __syncthreads();
        if (tid < 192) atomicAdd(&osums[tid], sb[tid]);
    }
}

template <int K, bool ACT, bool BIAS, bool HOUT, bool WOUT, bool STATS>
__global__ __launch_bounds__(256) void gemm96m(const float* __restrict__ in,
                                               const float* __restrict__ W,
                                               const float* __restrict__ bias,
                                               const float* __restrict__ bnsums,
                                               const float* __restrict__ gamma,
                                               const float* __restrict__ beta,
                                               const float* __restrict__ dsc,
                                               float* __restrict__ out,
                                               _Float16* __restrict__ hout,
                                               float* __restrict__ osums, int N) {
    gemm96_body<K, ACT, BIAS, HOUT, WOUT, STATS>(blockIdx.x, in, W, bias, bnsums,
                                                 gamma, beta, dsc, out, hout, osums, N);
}

// layer-1 GEMM merged with the CSR zero pass (both depend on nothing):
// blocks [0,gG) run the GEMM; blocks [gG, gridDim) zero cnt + BN sums.
__global__ __launch_bounds__(256) void gemm1_zero(const float* __restrict__ x,
                                                  const float* __restrict__ W1,
                                                  _Float16* __restrict__ hout,
                                                  int* __restrict__ cnt,
                                                  float* __restrict__ sums,
                                                  int gG, int N) {
    if ((int)blockIdx.x < gG) {
        gemm96_body<128, false, false, true, false, false>(
            blockIdx.x, x, W1, nullptr, nullptr, nullptr, nullptr, nullptr,
            nullptr, hout, nullptr, N);
    } else {
        int g = (blockIdx.x - gG) * 256 + threadIdx.x;
        int stride = (gridDim.x - gG) * 256;
        for (int i = g; i < N; i += stride) cnt[i] = 0;
        if (g < 576) sums[g] = 0.0f;
    }
}

// ---------------- MFMA final GEMM: l2norm(act(in) @ Wp2[96,64] + bp2) -------

__global__ __launch_bounds__(256) void gemm_finalm(const float* __restrict__ in,
                                                   const float* __restrict__ W,
                                                   const float* __restrict__ bias,
                                                   const float* __restrict__ bnsums,
                                                   const float* __restrict__ gamma,
                                                   const float* __restrict__ beta,
                                                   float* __restrict__ out, int N) {
    constexpr int K = 96, NK = 3, LDK = K + 8;
    __shared__ __align__(16) _Float16 Wt[64 * LDK];
    __shared__ __align__(16) float ssl[192];
    const int tid = threadIdx.x;
    for (int idx = tid; idx < K * 64; idx += 256) {
        int k = idx / 64, n = idx - k * 64;
        Wt[n * LDK + k] = (_Float16)W[idx];
    }
    if (tid < 96) {
        float inv_n = 1.0f / (float)N;
        float mean = bnsums[tid] * inv_n;
        float var = bnsums[96 + tid] * inv_n - mean * mean;
        float sc = gamma[tid] * rsqrtf(var + 1e-5f);
        ssl[tid] = sc;
        ssl[96 + tid] = beta[tid] - mean * sc;
    }
    __syncthreads();

    const int wave = tid >> 6, lane = tid & 63;
    const int quad = lane >> 4, lm = lane & 15;
    const int rbase = blockIdx.x * 64 + wave * 16;
    int arow = rbase + lm;
    arow = arow < N ? arow : N - 1;

    v8h afr[NK];
#pragma unroll
    for (int kc = 0; kc < NK; ++kc) {
        const float* p = &in[(long long)arow * K + kc * 32 + quad * 8];
        float4 p0 = *(const float4*)p;
        float4 p1 = *(const float4*)(p + 4);
        int kk = kc * 32 + quad * 8;
        float4 sc0 = *(const float4*)&ssl[kk];
        float4 sc1 = *(const float4*)&ssl[kk + 4];
        float4 sh0 = *(const float4*)&ssl[96 + kk];
        float4 sh1 = *(const float4*)&ssl[96 + kk + 4];
        p0.x = fmaxf(fmaf(p0.x, sc0.x, sh0.x), 0.0f);
        p0.y = fmaxf(fmaf(p0.y, sc0.y, sh0.y), 0.0f);
        p0.z = fmaxf(fmaf(p0.z, sc0.z, sh0.z), 0.0f);
        p0.w = fmaxf(fmaf(p0.w, sc0.w, sh0.w), 0.0f);
        p1.x = fmaxf(fmaf(p1.x, sc1.x, sh1.x), 0.0f);
        p1.y = fmaxf(fmaf(p1.y, sc1.y, sh1.y), 0.0f);
        p1.z = fmaxf(fmaf(p1.z, sc1.z, sh1.z), 0.0f);
        p1.w = fmaxf(fmaf(p1.w, sc1.w, sh1.w), 0.0f);
        v8h a;
        a[0] = (_Float16)p0.x; a[1] = (_Float16)p0.y;
        a[2] = (_Float16)p0.z; a[3] = (_Float16)p0.w;
        a[4] = (_Float16)p1.x; a[5] = (_Float16)p1.y;
        a[6] = (_Float16)p1.z; a[7] = (_Float16)p1.w;
        afr[kc] = a;
    }

    v4f acc[4];
#pragma unroll
    for (int t = 0; t < 4; ++t) {
        v4f c = {0.0f, 0.0f, 0.0f, 0.0f};
#pragma unroll
        for (int kc = 0; kc < NK; ++kc) {
            v8h b = *(const v8h*)&Wt[(t * 16 + lm) * LDK + kc * 32 + quad * 8];
            c = __builtin_amdgcn_mfma_f32_16x16x32_f16(afr[kc], b, c, 0, 0, 0);
        }
        float bv = bias[t * 16 + lm];
        c[0] += bv; c[1] += bv; c[2] += bv; c[3] += bv;
        acc[t] = c;
    }

    float sq[4];
#pragma unroll
    for (int r = 0; r < 4; ++r) {
        float s = acc[0][r] * acc[0][r] + acc[1][r] * acc[1][r] +
                  acc[2][r] * acc[2][r] + acc[3][r] * acc[3][r];
#pragma unroll
        for (int m = 1; m < 16; m <<= 1) s += __shfl_xor(s, m, 64);
        sq[r] = 1.0f / fmaxf(sqrtf(s), 1e-12f);
    }
#pragma unroll
    for (int r = 0; r < 4; ++r) {
        int gr = rbase + quad * 4 + r;
        if (gr < N) {
#pragma unroll
            for (int t = 0; t < 4; ++t)
                out[(long long)gr * 64 + t * 16 + lm] = acc[t][r] * sq[r];
        }
    }
}

// ---------------- CSR pull aggregation (fp16 gather, 2-B edge index) ---------
// PRESC=true : rows pre-scaled by dis[src] -> out = b + dn*(h[n] + sum h[s])
// PRESC=false: raw rows -> acc = dn*h[n] + sum dis[s]*h[s]; out = b + dn*acc
// 12 threads/node, 8 cols each, edge loop unrolled x8/x4 (R9-proven batching).

__device__ __forceinline__ void acc_row(float* acc, const __half2* h) {
#pragma unroll
    for (int k = 0; k < 4; ++k) {
        float2 f = __half22float2(h[k]);
        acc[2 * k + 0] += f.x;
        acc[2 * k + 1] += f.y;
    }
}

__device__ __forceinline__ void acc_roww(float* acc, const __half2* h, float w) {
#pragma unroll
    for (int k = 0; k < 4; ++k) {
        float2 f = __half22float2(h[k]);
        acc[2 * k + 0] = fmaf(f.x, w, acc[2 * k + 0]);
        acc[2 * k + 1] = fmaf(f.y, w, acc[2 * k + 1]);
    }
}

template <bool PRESC>
__global__ __launch_bounds__(256) void agg96h(const __half* __restrict__ hxw,
                                              const int* __restrict__ rowptr,
                                              const unsigned short* __restrict__ csrc,
                                              const float* __restrict__ dis,
                                              const float* __restrict__ bias,
                                              float* __restrict__ out, int N) {
    int idx = blockIdx.x * 256 + threadIdx.x;
    if (idx >= N * 12) return;
    int n = idx / 12, c8 = idx % 12;
    int ch = c8 * 8;
    float dn = dis[n];
    float acc[8];
    {
        float sw = PRESC ? 1.0f : dn;
        float4 g = *(const float4*)&hxw[(long long)n * 96 + ch];
        const __half2* hs = (const __half2*)&g;
#pragma unroll
        for (int k = 0; k < 4; ++k) {
            float2 f = __half22float2(hs[k]);
            acc[2 * k + 0] = f.x * sw;
            acc[2 * k + 1] = f.y * sw;
        }
    }
    int e = rowptr[n], e1 = rowptr[n + 1];
    for (; e + 7 < e1; e += 8) {
        int s[8];
        float4 g[8];
        float w[8];
#pragma unroll
        for (int j = 0; j < 8; ++j) s[j] = csrc[e + j];
        if (!PRESC) {
#pragma unroll
            for (int j = 0; j < 8; ++j) w[j] = dis[s[j]];
        }
#pragma unroll
        for (int j = 0; j < 8; ++j)
            g[j] = *(const float4*)&hxw[(long long)s[j] * 96 + ch];
#pragma unroll
        for (int j = 0; j < 8; ++j) {
            if (PRESC) acc_row(acc, (const __half2*)&g[j]);
            else       acc_roww(acc, (const __half2*)&g[j], w[j]);
        }
    }
    for (; e + 3 < e1; e += 4) {
        int s[4];
        float4 g[4];
        float w[4];
#pragma unroll
        for (int j = 0; j < 4; ++j) s[j] = csrc[e + j];
        if (!PRESC) {
#pragma unroll
            for (int j = 0; j < 4; ++j) w[j] = dis[s[j]];
        }
#pragma unroll
        for (int j = 0; j < 4; ++j)
            g[j] = *(const float4*)&hxw[(long long)s[j] * 96 + ch];
#pragma unroll
        for (int j = 0; j < 4; ++j) {
            if (PRESC) acc_row(acc, (const __half2*)&g[j]);
            else       acc_roww(acc, (const __half2*)&g[j], w[j]);
        }
    }
    for (; e < e1; ++e) {
        int s0 = csrc[e];
        float4 g0 = *(const float4*)&hxw[(long long)s0 * 96 + ch];
        if (PRESC) acc_row(acc, (const __half2*)&g0);
        else       acc_roww(acc, (const __half2*)&g0, dis[s0]);
    }
    float4 o0, o1;
    o0.x = fmaf(acc[0], dn, bias[ch + 0]);
    o0.y = fmaf(acc[1], dn, bias[ch + 1]);
    o0.z = fmaf(acc[2], dn, bias[ch + 2]);
    o0.w = fmaf(acc[3], dn, bias[ch + 3]);
    o1.x = fmaf(acc[4], dn, bias[ch + 4]);
    o1.y = fmaf(acc[5], dn, bias[ch + 5]);
    o1.z = fmaf(acc[6], dn, bias[ch + 6]);
    o1.w = fmaf(acc[7], dn, bias[ch + 7]);
    *(float4*)&out[(long long)n * 96 + ch] = o0;
    *(float4*)&out[(long long)n * 96 + ch + 4] = o1;
}

// ---------------- BN stats (coalesced grid-stride, for agg outputs) ----------
// grid must be a multiple of 3 blocks so stride = grid*256 is a multiple of 24.

__global__ __launch_bounds__(256) void bn_stats96(const float* __restrict__ h,
                                                  float* __restrict__ sums, int N) {
    __shared__ float sb[192];
    const int tid = threadIdx.x;
    if (tid < 192) sb[tid] = 0.0f;
    __syncthreads();
    int g = blockIdx.x * 256 + tid;
    int total = N * 24, stride = gridDim.x * 256;
    float4 s4 = {0, 0, 0, 0}, q4 = {0, 0, 0, 0};
    int c4 = g % 24;
    for (int i = g; i < total; i += stride) {
        int n = i / 24;
        float4 v = *(const float4*)&h[n * 96 + 4 * c4];
        s4.x += v.x; s4.y += v.y; s4.z += v.z; s4.w += v.w;
        q4.x += v.x * v.x; q4.y += v.y * v.y; q4.z += v.z * v.z; q4.w += v.w * v.w;
    }
    atomicAdd(&sb[4 * c4 + 0], s4.x);
    atomicAdd(&sb[4 * c4 + 1], s4.y);
    atomicAdd(&sb[4 * c4 + 2], s4.z);
    atomicAdd(&sb[4 * c4 + 3], s4.w);
    atomicAdd(&sb[96 + 4 * c4 + 0], q4.x);
    atomicAdd(&sb[96 + 4 * c4 + 1], q4.y);
    atomicAdd(&sb[96 + 4 * c4 + 2], q4.z);
    atomicAdd(&sb[96 + 4 * c4 + 3], q4.w);
    __syncthreads();
    if (tid < 192) atomicAdd(&sums[tid], sb[tid]);
}

// ---------------- launch ----------------

extern "C" void kernel_launch(void* const* d_in, const int* in_sizes, int n_in,
                              void* d_out, int out_size, void* d_ws, size_t ws_size,
                              hipStream_t stream) {
    const float* x   = (const float*)d_in[0];
    const int*   ei  = (const int*)d_in[1];
    const float* W1  = (const float*)d_in[2];
    const float* b1  = (const float*)d_in[3];
    const float* g1  = (const float*)d_in[4];
    const float* be1 = (const float*)d_in[5];
    const float* W2  = (const float*)d_in[6];
    const float* b2  = (const float*)d_in[7];
    const float* g2  = (const float*)d_in[8];
    const float* be2 = (const float*)d_in[9];
    const float* Wp1 = (const float*)d_in[10];
    const float* bp1 = (const float*)d_in[11];
    const float* gp  = (const float*)d_in[12];
    const float* bep = (const float*)d_in[13];
    const float* Wp2 = (const float*)d_in[14];
    const float* bp2 = (const float*)d_in[15];

    const int N = in_sizes[0] / 128;   // 50000 (< 2^16 -> uint16 indices ok)
    const int E = in_sizes[1] / 2;     // 800000
    const int* src = ei;
    const int* dst = ei + E;

    // workspace layout (~50 MB)
    char* w = (char*)d_ws;
    auto alloc = [&](size_t bytes) { char* p = w; w += (bytes + 15) & ~size_t(15); return p; };
    int*            cnt    = (int*)alloc((size_t)N * 4);
    int*            rowptr = (int*)alloc((size_t)(N + 1) * 4);
    int*            bsum   = (int*)alloc(64 * 4);
    float*          dis    = (float*)alloc((size_t)N * 4);
    unsigned short* eoff   = (unsigned short*)alloc((size_t)E * 2);
    unsigned short* csrc   = (unsigned short*)alloc((size_t)E * 2);
    float*          buf1   = (float*)alloc((size_t)N * 96 * 4);
    float*          buf2   = (float*)alloc((size_t)N * 96 * 4);
    _Float16*       hbuf   = (_Float16*)alloc((size_t)N * 96 * 2);
    float*          sums   = (float*)alloc(576 * 4);
    float* sums1 = sums, *sums2 = sums + 192, *sums3 = sums + 384;

    float* out = (float*)d_out;

    const int gE  = cdiv(E, BLK);                  // 3125 blocks
    const int gG  = cdiv(N, 64);                   // 782 gemm blocks
    const int gA  = cdiv((long long)N * 12, BLK);  // 2344 agg blocks
    const int nb  = cdiv(N, 1024);                 // scan chunks (49)

    // D1: layer-1 GEMM (plain fp16 shadow) merged with CSR zero pass
    gemm1_zero<<<gG + nb, 256, 0, stream>>>(x, W1, hbuf, cnt, sums, gG, N);
    // D2-D5: CSR build (count -> chunk scan+dis -> apply (redundant rescan) -> fill)
    count_dst_off<<<gE, BLK, 0, stream>>>(dst, cnt, eoff, E);
    scan1_dis<<<nb, 256, 0, stream>>>(cnt, rowptr, bsum, dis, N);
    scan23<<<cdiv(N, 256), 256, 0, stream>>>(rowptr, bsum, nb, N, E);
    csr_fill<<<gE, BLK, 0, stream>>>(src, dst, eoff, rowptr, csrc, E);

    // D6-D7: layer-1 agg (dis gathered per edge; hbuf unscaled) + BN1 stats
    agg96h<false><<<gA, 256, 0, stream>>>((const __half*)hbuf, rowptr, csrc, dis,
                                          b1, buf2, N);
    bn_stats96<<<510, 256, 0, stream>>>(buf2, sums1, N);

    // D8-D10: layer 2 (BN1 fused; dis-prescaled fp16 shadow) + agg + BN2 stats
    gemm96m<96, true, false, true, false, false><<<gG, 256, 0, stream>>>(
        buf2, W2, nullptr, sums1, g1, be1, dis, nullptr, hbuf, nullptr, N);
    agg96h<true><<<gA, 256, 0, stream>>>((const __half*)hbuf, rowptr, csrc, dis,
                                         b2, buf2, N);
    bn_stats96<<<510, 256, 0, stream>>>(buf2, sums2, N);

    // D11: projector linear 1 (BN2 fused; fp32 out; BN3 stats fused)
    gemm96m<96, true, true, false, true, true><<<gG, 256, 0, stream>>>(
        buf2, Wp1, bp1, sums2, g2, be2, nullptr, buf1, nullptr, sums3, N);

    // D12: projector linear 2 (BN3 fused + bias + L2 normalize)
    gemm_finalm<<<gG, 256, 0, stream>>>(buf1, Wp2, bp2, sums3, gp, bep, out, N);
}

// Round 7
// 308.158 us; speedup vs baseline: 2.0073x; 1.0829x over previous
//
#include <hip/hip_runtime.h>
#include <hip/hip_fp16.h>

constexpr int BLK = 256;

static inline int cdiv(long long a, int b) { return (int)((a + b - 1) / b); }

using v8h = __attribute__((ext_vector_type(8))) _Float16;
using v4f = __attribute__((ext_vector_type(4))) float;

// ---------------- degree / CSR build ----------------
// R4: cooperative grid.sync ~60us each on MI355X — never use.
// R5: no cross-block spin-waits (hang risk).
// R6: launch overhead is only ~2us/dispatch — optimize kernel time, not count.
//   This round: count_dst_off overlapped with layer-1 GEMM (independent work,
//   complementary pipes); cnt/sums zeroing via one hipMemsetAsync.

// block scans 1024 elements (256 threads x 4); also emits dis = rsqrt(cnt+1)
__global__ __launch_bounds__(256) void scan1_dis(const int* __restrict__ cnt,
                                                 int* __restrict__ rowptr,
                                                 int* __restrict__ bsum,
                                                 float* __restrict__ dis, int N) {
    __shared__ int ts[256];
    int tid = threadIdx.x;
    int base = blockIdx.x * 1024 + tid * 4;
    int v[4], s = 0;
#pragma unroll
    for (int i = 0; i < 4; ++i) {
        v[i] = (base + i < N) ? cnt[base + i] : 0;
        s += v[i];
        if (base + i < N) dis[base + i] = rsqrtf((float)v[i] + 1.0f);
    }
    ts[tid] = s;
    __syncthreads();
    for (int off = 1; off < 256; off <<= 1) {
        int t = 0;
        if (tid >= off) t = ts[tid - off];
        __syncthreads();
        if (tid >= off) ts[tid] += t;
        __syncthreads();
    }
    int run = ts[tid] - s;
#pragma unroll
    for (int i = 0; i < 4; ++i) {
        if (base + i < N) rowptr[base + i] = run;
        run += v[i];
    }
    if (tid == 255) bsum[blockIdx.x] = ts[255];
}

// merged scan2+scan3: every block wave-scans the <=64 chunk sums (L2-resident,
// redundant but free) and applies its chunk's exclusive offset to rowptr.
__global__ __launch_bounds__(256) void scan23(int* __restrict__ rowptr,
                                              const int* __restrict__ bsum,
                                              int nb, int N, int E) {
    __shared__ int sboff[64];
    const int tid = threadIdx.x;
    if (tid < 64) {
        int orig = (tid < nb) ? bsum[tid] : 0;
        int v = orig;
#pragma unroll
        for (int off = 1; off < 64; off <<= 1) {
            int t = __shfl_up(v, off, 64);
            if (tid >= off) v += t;
        }
        sboff[tid] = v - orig;  // exclusive prefix of chunk sums
    }
    __syncthreads();
    int i = blockIdx.x * 256 + tid;
    if (i < N) rowptr[i] += sboff[i >> 10];
    if (i == 0) rowptr[N] = E;
}

// atomic-free scatter of 2-B src index: slot = rowptr[dst] + eoff (bijection)
__global__ void csr_fill(const int* __restrict__ src, const int* __restrict__ dst,
                         const unsigned short* __restrict__ eoff,
                         const int* __restrict__ rowptr,
                         unsigned short* __restrict__ csrc, int E) {
    for (int i = blockIdx.x * blockDim.x + threadIdx.x; i < E; i += gridDim.x * blockDim.x) {
        csrc[rowptr[dst[i]] + (int)eoff[i]] = (unsigned short)src[i];
    }
}

// ---------------- MFMA GEMM body: act(in)[N,K] @ W[K,96] (+bias) ------------
// TIN = float (layer 1, raw x) or _Float16 (fp16 activation buffers).
// A: load -> (BN+ReLU in fp32) -> fp16 frags. B: W^T fp16 in LDS (one barrier).
// Output: ALWAYS fp16 (hout), optionally pre-scaled by dsc[row] (nullable).
// STATS: epilogue accumulates column sum/sumsq (fp32, pre-scale) into osums.

template <int K, bool ACT, bool BIAS, bool STATS, typename TIN>
__device__ __forceinline__ void gemm96_body(int bid,
                                            const TIN* __restrict__ in,
                                            const float* __restrict__ W,
                                            const float* __restrict__ bias,
                                            const float* __restrict__ bnsums,
                                            const float* __restrict__ gamma,
                                            const float* __restrict__ beta,
                                            const float* __restrict__ dsc,
                                            _Float16* __restrict__ hout,
                                            float* __restrict__ osums, int N) {
    constexpr int NK = K / 32;
    constexpr int LDK = K + 8;
    __shared__ __align__(16) _Float16 Wt[96 * LDK];
    __shared__ __align__(16) float ssl[ACT ? 192 : 1];
    __shared__ float sb[STATS ? 192 : 1];
    const int tid = threadIdx.x;
    for (int idx = tid; idx < K * 96; idx += 256) {
        int k = idx / 96, n = idx - k * 96;
        Wt[n * LDK + k] = (_Float16)W[idx];
    }
    if (ACT && tid < 96) {
        float inv_n = 1.0f / (float)N;
        float mean = bnsums[tid] * inv_n;
        float var = bnsums[96 + tid] * inv_n - mean * mean;
        float sc = gamma[tid] * rsqrtf(var + 1e-5f);
        ssl[tid] = sc;
        ssl[96 + tid] = beta[tid] - mean * sc;
    }
    if (STATS && tid < 192) sb[tid] = 0.0f;
    __syncthreads();

    const int wave = tid >> 6, lane = tid & 63;
    const int quad = lane >> 4, lm = lane & 15;
    const int rbase = bid * 64 + wave * 16;
    int arow = rbase + lm;
    arow = arow < N ? arow : N - 1;

    v8h afr[NK];
#pragma unroll
    for (int kc = 0; kc < NK; ++kc) {
        const int kk = kc * 32 + quad * 8;
        if constexpr (sizeof(TIN) == 4) {
            const float* p = (const float*)&in[(long long)arow * K + kk];
            float4 p0 = *(const float4*)p;
            float4 p1 = *(const float4*)(p + 4);
            if (ACT) {
                float4 sc0 = *(const float4*)&ssl[kk];
                float4 sc1 = *(const float4*)&ssl[kk + 4];
                float4 sh0 = *(const float4*)&ssl[96 + kk];
                float4 sh1 = *(const float4*)&ssl[96 + kk + 4];
                p0.x = fmaxf(fmaf(p0.x, sc0.x, sh0.x), 0.0f);
                p0.y = fmaxf(fmaf(p0.y, sc0.y, sh0.y), 0.0f);
                p0.z = fmaxf(fmaf(p0.z, sc0.z, sh0.z), 0.0f);
                p0.w = fmaxf(fmaf(p0.w, sc0.w, sh0.w), 0.0f);
                p1.x = fmaxf(fmaf(p1.x, sc1.x, sh1.x), 0.0f);
                p1.y = fmaxf(fmaf(p1.y, sc1.y, sh1.y), 0.0f);
                p1.z = fmaxf(fmaf(p1.z, sc1.z, sh1.z), 0.0f);
                p1.w = fmaxf(fmaf(p1.w, sc1.w, sh1.w), 0.0f);
            }
            v8h a;
            a[0] = (_Float16)p0.x; a[1] = (_Float16)p0.y;
            a[2] = (_Float16)p0.z; a[3] = (_Float16)p0.w;
            a[4] = (_Float16)p1.x; a[5] = (_Float16)p1.y;
            a[6] = (_Float16)p1.z; a[7] = (_Float16)p1.w;
            afr[kc] = a;
        } else {
            v8h hv = *(const v8h*)&in[(long long)arow * K + kk];
            if (ACT) {
#pragma unroll
                for (int j = 0; j < 8; ++j) {
                    float f = (float)hv[j];
                    f = fmaxf(fmaf(f, ssl[kk + j], ssl[96 + kk + j]), 0.0f);
                    hv[j] = (_Float16)f;
                }
            }
            afr[kc] = hv;
        }
    }

    v4f acc[6];
#pragma unroll
    for (int t = 0; t < 6; ++t) {
        v4f c = {0.0f, 0.0f, 0.0f, 0.0f};
#pragma unroll
        for (int kc = 0; kc < NK; ++kc) {
            v8h b = *(const v8h*)&Wt[(t * 16 + lm) * LDK + kc * 32 + quad * 8];
            c = __builtin_amdgcn_mfma_f32_16x16x32_f16(afr[kc], b, c, 0, 0, 0);
        }
        acc[t] = c;
    }

    float dr[4];
#pragma unroll
    for (int r = 0; r < 4; ++r) {
        int gr = rbase + quad * 4 + r;
        dr[r] = dsc ? dsc[gr < N ? gr : N - 1] : 1.0f;
    }

    float ls[6], lq[6];
#pragma unroll
    for (int t = 0; t < 6; ++t) { ls[t] = 0.0f; lq[t] = 0.0f; }
#pragma unroll
    for (int t = 0; t < 6; ++t) {
        float bv = BIAS ? bias[t * 16 + lm] : 0.0f;
#pragma unroll
        for (int r = 0; r < 4; ++r) {
            int gr = rbase + quad * 4 + r;
            if (gr < N) {
                float o = acc[t][r] + bv;
                hout[(long long)gr * 96 + t * 16 + lm] = (_Float16)(o * dr[r]);
                if (STATS) { ls[t] += o; lq[t] += o * o; }
            }
        }
    }
    if (STATS) {
#pragma unroll
        for (int t = 0; t < 6; ++t) {
            ls[t] += __shfl_xor(ls[t], 16);
            ls[t] += __shfl_xor(ls[t], 32);
            lq[t] += __shfl_xor(lq[t], 16);
            lq[t] += __shfl_xor(lq[t], 32);
        }
        if (quad == 0) {
#pragma unroll
            for (int t = 0; t < 6; ++t) {
                atomicAdd(&sb[t * 16 + lm], ls[t]);
                atomicAdd(&sb[96 + t * 16 + lm], lq[t]);
            }
        }
        __syncthreads();
        if (tid < 192) atomicAdd(&osums[tid], sb[tid]);
    }
}

template <int K, bool ACT, bool BIAS, bool STATS, typename TIN>
__global__ __launch_bounds__(256) void gemm96m(const TIN* __restrict__ in,
                                               const float* __restrict__ W,
                                               const float* __restrict__ bias,
                                               const float* __restrict__ bnsums,
                                               const float* __restrict__ gamma,
                                               const float* __restrict__ beta,
                                               const float* __restrict__ dsc,
                                               _Float16* __restrict__ hout,
                                               float* __restrict__ osums, int N) {
    gemm96_body<K, ACT, BIAS, STATS, TIN>(blockIdx.x, in, W, bias, bnsums,
                                          gamma, beta, dsc, hout, osums, N);
}

// layer-1 GEMM overlapped with the edge-count pass (independent inputs/outputs;
// GEMM is MFMA+stream-bound, count is atomic-bound -> complementary pipes).
// blocks [0,gG): GEMM.  blocks [gG, gG+gC): grid-stride in-degree count.
__global__ __launch_bounds__(256) void gemm1_count(const float* __restrict__ x,
                                                   const float* __restrict__ W1,
                                                   _Float16* __restrict__ hout,
                                                   const int* __restrict__ dst,
                                                   int* __restrict__ cnt,
                                                   unsigned short* __restrict__ eoff,
                                                   int gG, int N, int E) {
    if ((int)blockIdx.x < gG) {
        gemm96_body<128, false, false, false, float>(
            blockIdx.x, x, W1, nullptr, nullptr, nullptr, nullptr, nullptr,
            hout, nullptr, N);
    } else {
        int g = (blockIdx.x - gG) * 256 + threadIdx.x;
        int stride = (gridDim.x - gG) * 256;
        for (int i = g; i < E; i += stride)
            eoff[i] = (unsigned short)atomicAdd(&cnt[dst[i]], 1);
    }
}

// ---------------- MFMA final GEMM: l2norm(act(in) @ Wp2[96,64] + bp2) -------

__global__ __launch_bounds__(256) void gemm_finalm(const _Float16* __restrict__ in,
                                                   const float* __restrict__ W,
                                                   const float* __restrict__ bias,
                                                   const float* __restrict__ bnsums,
                                                   const float* __restrict__ gamma,
                                                   const float* __restrict__ beta,
                                                   float* __restrict__ out, int N) {
    constexpr int K = 96, NK = 3, LDK = K + 8;
    __shared__ __align__(16) _Float16 Wt[64 * LDK];
    __shared__ __align__(16) float ssl[192];
    const int tid = threadIdx.x;
    for (int idx = tid; idx < K * 64; idx += 256) {
        int k = idx / 64, n = idx - k * 64;
        Wt[n * LDK + k] = (_Float16)W[idx];
    }
    if (tid < 96) {
        float inv_n = 1.0f / (float)N;
        float mean = bnsums[tid] * inv_n;
        float var = bnsums[96 + tid] * inv_n - mean * mean;
        float sc = gamma[tid] * rsqrtf(var + 1e-5f);
        ssl[tid] = sc;
        ssl[96 + tid] = beta[tid] - mean * sc;
    }
    __syncthreads();

    const int wave = tid >> 6, lane = tid & 63;
    const int quad = lane >> 4, lm = lane & 15;
    const int rbase = blockIdx.x * 64 + wave * 16;
    int arow = rbase + lm;
    arow = arow < N ? arow : N - 1;

    v8h afr[NK];
#pragma unroll
    for (int kc = 0; kc < NK; ++kc) {
        const int kk = kc * 32 + quad * 8;
        v8h hv = *(const v8h*)&in[(long long)arow * K + kk];
#pragma unroll
        for (int j = 0; j < 8; ++j) {
            float f = (float)hv[j];
            f = fmaxf(fmaf(f, ssl[kk + j], ssl[96 + kk + j]), 0.0f);
            hv[j] = (_Float16)f;
        }
        afr[kc] = hv;
    }

    v4f acc[4];
#pragma unroll
    for (int t = 0; t < 4; ++t) {
        v4f c = {0.0f, 0.0f, 0.0f, 0.0f};
#pragma unroll
        for (int kc = 0; kc < NK; ++kc) {
            v8h b = *(const v8h*)&Wt[(t * 16 + lm) * LDK + kc * 32 + quad * 8];
            c = __builtin_amdgcn_mfma_f32_16x16x32_f16(afr[kc], b, c, 0, 0, 0);
        }
        float bv = bias[t * 16 + lm];
        c[0] += bv; c[1] += bv; c[2] += bv; c[3] += bv;
        acc[t] = c;
    }

    float sq[4];
#pragma unroll
    for (int r = 0; r < 4; ++r) {
        float s = acc[0][r] * acc[0][r] + acc[1][r] * acc[1][r] +
                  acc[2][r] * acc[2][r] + acc[3][r] * acc[3][r];
#pragma unroll
        for (int m = 1; m < 16; m <<= 1) s += __shfl_xor(s, m, 64);
        sq[r] = 1.0f / fmaxf(sqrtf(s), 1e-12f);
    }
#pragma unroll
    for (int r = 0; r < 4; ++r) {
        int gr = rbase + quad * 4 + r;
        if (gr < N) {
#pragma unroll
            for (int t = 0; t < 4; ++t)
                out[(long long)gr * 64 + t * 16 + lm] = acc[t][r] * sq[r];
        }
    }
}

// ---------------- CSR pull aggregation (fp16 gather, 2-B edge index) ---------
// PRESC=true : rows pre-scaled by dis[src] -> out = b + dn*(h[n] + sum h[s])
// PRESC=false: raw rows -> acc = dn*h[n] + sum dis[s]*h[s]; out = b + dn*acc
// Output fp16 (accumulate fp32, one rounding on store). 12 threads/node,
// 8 cols each, edge loop unrolled x8/x4 (R9-proven batching).

__device__ __forceinline__ void acc_row(float* acc, const __half2* h) {
#pragma unroll
    for (int k = 0; k < 4; ++k) {
        float2 f = __half22float2(h[k]);
        acc[2 * k + 0] += f.x;
        acc[2 * k + 1] += f.y;
    }
}

__device__ __forceinline__ void acc_roww(float* acc, const __half2* h, float w) {
#pragma unroll
    for (int k = 0; k < 4; ++k) {
        float2 f = __half22float2(h[k]);
        acc[2 * k + 0] = fmaf(f.x, w, acc[2 * k + 0]);
        acc[2 * k + 1] = fmaf(f.y, w, acc[2 * k + 1]);
    }
}

template <bool PRESC>
__global__ __launch_bounds__(256) void agg96h(const __half* __restrict__ hxw,
                                              const int* __restrict__ rowptr,
                                              const unsigned short* __restrict__ csrc,
                                              const float* __restrict__ dis,
                                              const float* __restrict__ bias,
                                              _Float16* __restrict__ outh, int N) {
    int idx = blockIdx.x * 256 + threadIdx.x;
    if (idx >= N * 12) return;
    int n = idx / 12, c8 = idx % 12;
    int ch = c8 * 8;
    float dn = dis[n];
    float acc[8];
    {
        float sw = PRESC ? 1.0f : dn;
        float4 g = *(const float4*)&hxw[(long long)n * 96 + ch];
        const __half2* hs = (const __half2*)&g;
#pragma unroll
        for (int k = 0; k < 4; ++k) {
            float2 f = __half22float2(hs[k]);
            acc[2 * k + 0] = f.x * sw;
            acc[2 * k + 1] = f.y * sw;
        }
    }
    int e = rowptr[n], e1 = rowptr[n + 1];
    for (; e + 7 < e1; e += 8) {
        int s[8];
        float4 g[8];
        float w[8];
#pragma unroll
        for (int j = 0; j < 8; ++j) s[j] = csrc[e + j];
        if (!PRESC) {
#pragma unroll
            for (int j = 0; j < 8; ++j) w[j] = dis[s[j]];
        }
#pragma unroll
        for (int j = 0; j < 8; ++j)
            g[j] = *(const float4*)&hxw[(long long)s[j] * 96 + ch];
#pragma unroll
        for (int j = 0; j < 8; ++j) {
            if (PRESC) acc_row(acc, (const __half2*)&g[j]);
            else       acc_roww(acc, (const __half2*)&g[j], w[j]);
        }
    }
    for (; e + 3 < e1; e += 4) {
        int s[4];
        float4 g[4];
        float w[4];
#pragma unroll
        for (int j = 0; j < 4; ++j) s[j] = csrc[e + j];
        if (!PRESC) {
#pragma unroll
            for (int j = 0; j < 4; ++j) w[j] = dis[s[j]];
        }
#pragma unroll
        for (int j = 0; j < 4; ++j)
            g[j] = *(const float4*)&hxw[(long long)s[j] * 96 + ch];
#pragma unroll
        for (int j = 0; j < 4; ++j) {
            if (PRESC) acc_row(acc, (const __half2*)&g[j]);
            else       acc_roww(acc, (const __half2*)&g[j], w[j]);
        }
    }
    for (; e < e1; ++e) {
        int s0 = csrc[e];
        float4 g0 = *(const float4*)&hxw[(long long)s0 * 96 + ch];
        if (PRESC) acc_row(acc, (const __half2*)&g0);
        else       acc_roww(acc, (const __half2*)&g0, dis[s0]);
    }
    v8h o;
#pragma unroll
    for (int j = 0; j < 8; ++j)
        o[j] = (_Float16)fmaf(acc[j], dn, bias[ch + j]);
    *(v8h*)&outh[(long long)n * 96 + ch] = o;
}

// ---------------- BN stats over fp16 buffer (coalesced grid-stride) ----------
// grid must be a multiple of 3 so stride = grid*256 is a multiple of 12
// (fixed c8 = g%12 requires i%12 invariant across the stride loop).

__global__ __launch_bounds__(256) void bn_stats96h(const __half* __restrict__ h,
                                                   float* __restrict__ sums, int N) {
    __shared__ float sb[192];
    const int tid = threadIdx.x;
    if (tid < 192) sb[tid] = 0.0f;
    __syncthreads();
    int g = blockIdx.x * 256 + tid;
    int total = N * 12, stride = gridDim.x * 256;
    int c8 = g % 12;
    float s[8] = {0, 0, 0, 0, 0, 0, 0, 0};
    float q[8] = {0, 0, 0, 0, 0, 0, 0, 0};
    for (int i = g; i < total; i += stride) {
        int n = i / 12;
        float4 raw = *(const float4*)&h[n * 96 + 8 * c8];
        const __half2* hp = (const __half2*)&raw;
#pragma unroll
        for (int k = 0; k < 4; ++k) {
            float2 f = __half22float2(hp[k]);
            s[2 * k + 0] += f.x;
            s[2 * k + 1] += f.y;
            q[2 * k + 0] += f.x * f.x;
            q[2 * k + 1] += f.y * f.y;
        }
    }
#pragma unroll
    for (int j = 0; j < 8; ++j) {
        atomicAdd(&sb[8 * c8 + j], s[j]);
        atomicAdd(&sb[96 + 8 * c8 + j], q[j]);
    }
    __syncthreads();
    if (tid < 192) atomicAdd(&sums[tid], sb[tid]);
}

// ---------------- launch ----------------

extern "C" void kernel_launch(void* const* d_in, const int* in_sizes, int n_in,
                              void* d_out, int out_size, void* d_ws, size_t ws_size,
                              hipStream_t stream) {
    const float* x   = (const float*)d_in[0];
    const int*   ei  = (const int*)d_in[1];
    const float* W1  = (const float*)d_in[2];
    const float* b1  = (const float*)d_in[3];
    const float* g1  = (const float*)d_in[4];
    const float* be1 = (const float*)d_in[5];
    const float* W2  = (const float*)d_in[6];
    const float* b2  = (const float*)d_in[7];
    const float* g2  = (const float*)d_in[8];
    const float* be2 = (const float*)d_in[9];
    const float* Wp1 = (const float*)d_in[10];
    const float* bp1 = (const float*)d_in[11];
    const float* gp  = (const float*)d_in[12];
    const float* bep = (const float*)d_in[13];
    const float* Wp2 = (const float*)d_in[14];
    const float* bp2 = (const float*)d_in[15];

    const int N = in_sizes[0] / 128;   // 50000 (< 2^16 -> uint16 indices ok)
    const int E = in_sizes[1] / 2;     // 800000
    const int* src = ei;
    const int* dst = ei + E;

    // workspace layout (cnt and sums adjacent -> one memsetAsync zeroes both)
    char* w = (char*)d_ws;
    auto alloc = [&](size_t bytes) { char* p = w; w += (bytes + 15) & ~size_t(15); return p; };
    int*            cnt    = (int*)alloc((size_t)N * 4);
    float*          sums   = (float*)alloc(576 * 4);
    int*            rowptr = (int*)alloc((size_t)(N + 1) * 4);
    int*            bsum   = (int*)alloc(64 * 4);
    float*          dis    = (float*)alloc((size_t)N * 4);
    unsigned short* eoff   = (unsigned short*)alloc((size_t)E * 2);
    unsigned short* csrc   = (unsigned short*)alloc((size_t)E * 2);
    _Float16*       buf2h  = (_Float16*)alloc((size_t)N * 96 * 2);
    _Float16*       hbuf   = (_Float16*)alloc((size_t)N * 96 * 2);
    float* sums1 = sums, *sums2 = sums + 192, *sums3 = sums + 384;

    float* out = (float*)d_out;

    const int gE  = cdiv(E, BLK);                  // 3125 fill blocks
    const int gG  = cdiv(N, 64);                   // 782 gemm blocks
    const int gC  = 1024;                          // count blocks (grid-stride)
    const int gA  = cdiv((long long)N * 12, BLK);  // 2344 agg blocks
    const int nb  = cdiv(N, 1024);                 // scan chunks (49)

    // zero cnt + BN sums (adjacent allocations -> single contiguous memset)
    size_t zlen = (size_t)((char*)sums - (char*)cnt) + 576 * 4;
    hipMemsetAsync(cnt, 0, zlen, stream);

    // D1: layer-1 GEMM (fp16 shadow, unscaled) overlapped with edge count
    gemm1_count<<<gG + gC, 256, 0, stream>>>(x, W1, hbuf, dst, cnt, eoff, gG, N, E);
    // D2-D4: CSR build (chunk scan+dis -> apply offsets -> atomic-free fill)
    scan1_dis<<<nb, 256, 0, stream>>>(cnt, rowptr, bsum, dis, N);
    scan23<<<cdiv(N, 256), 256, 0, stream>>>(rowptr, bsum, nb, N, E);
    csr_fill<<<gE, BLK, 0, stream>>>(src, dst, eoff, rowptr, csrc, E);

    // D5-D6: layer-1 agg (dis gathered per edge) -> fp16 buf2h; BN1 stats
    agg96h<false><<<gA, 256, 0, stream>>>((const __half*)hbuf, rowptr, csrc, dis,
                                          b1, buf2h, N);
    bn_stats96h<<<510, 256, 0, stream>>>((const __half*)buf2h, sums1, N);

    // D7-D9: layer 2 (BN1 fused, fp16 in; dis-prescaled fp16 out) + agg + BN2
    gemm96m<96, true, false, false, _Float16><<<gG, 256, 0, stream>>>(
        buf2h, W2, nullptr, sums1, g1, be1, dis, hbuf, nullptr, N);
    agg96h<true><<<gA, 256, 0, stream>>>((const __half*)hbuf, rowptr, csrc, dis,
                                         b2, buf2h, N);
    bn_stats96h<<<510, 256, 0, stream>>>((const __half*)buf2h, sums2, N);

    // D10: projector linear 1 (BN2 fused; fp16 out into hbuf; BN3 stats fused)
    gemm96m<96, true, true, true, _Float16><<<gG, 256, 0, stream>>>(
        buf2h, Wp1, bp1, sums2, g2, be2, nullptr, hbuf, sums3, N);

    // D11: projector linear 2 (BN3 fused + bias + L2 normalize), fp16 in
    gemm_finalm<<<gG, 256, 0, stream>>>(hbuf, Wp2, bp2, sums3, gp, bep, out, N);
}